// Round 5
// baseline (159.339 us; speedup 1.0000x reference)
//
#include <hip/hip_runtime.h>
#include <math.h>

// softplus(-p) = max(-p,0) + log(1+exp(-|p|)); fast intrinsics fine:
// threshold is 135 absolute on a ~6752 output (2%).
__device__ __forceinline__ float spn(float p) {
    return fmaxf(-p, 0.0f) + __logf(1.0f + __expf(-fabsf(p)));
}

__device__ __forceinline__ float dot4(float4 a, float4 b) {
    return a.x * b.x + a.y * b.y + a.z * b.z + a.w * b.w;
}

// Full 64-lane reduction, VALU-only (DPP). Result valid in lane 63.
__device__ __forceinline__ float wave64_reduce(float x) {
    int t;
    t = __builtin_amdgcn_update_dpp(0, __builtin_bit_cast(int, x), 0x111, 0xf, 0xf, true);
    x += __builtin_bit_cast(float, t);
    t = __builtin_amdgcn_update_dpp(0, __builtin_bit_cast(int, x), 0x112, 0xf, 0xf, true);
    x += __builtin_bit_cast(float, t);
    t = __builtin_amdgcn_update_dpp(0, __builtin_bit_cast(int, x), 0x114, 0xf, 0xf, true);
    x += __builtin_bit_cast(float, t);
    t = __builtin_amdgcn_update_dpp(0, __builtin_bit_cast(int, x), 0x118, 0xf, 0xf, true);
    x += __builtin_bit_cast(float, t);
    t = __builtin_amdgcn_update_dpp(0, __builtin_bit_cast(int, x), 0x142, 0xa, 0xf, true); // row_bcast15
    x += __builtin_bit_cast(float, t);
    t = __builtin_amdgcn_update_dpp(0, __builtin_bit_cast(int, x), 0x143, 0xc, 0xf, true); // row_bcast31
    x += __builtin_bit_cast(float, t);
    return x;   // lane 63 holds the full sum
}

#define NBLOCKS 2048
#define NPW 8   // nodes per wave: 2048 blocks * 4 waves * 8 = 65536

// Wave-per-node loads (one row = one contiguous 1 KB wave64 float4 load).
// All 16 z rows + the 4 "common" g rows issued in one burst up-front; the
// batch arrays are SORTED, so the graph index is wave-constant ~94% of the
// time -> per-node g reloads only at graph boundaries (wave-uniform scalar
// branch, ~6% of nodes).
__global__ __launch_bounds__(256) void jsd_dot_kernel(
    const int*   __restrict__ b1,
    const int*   __restrict__ b2,
    const float* __restrict__ z1,
    const float* __restrict__ z2,
    const float* __restrict__ g1,
    const float* __restrict__ g2,
    float*       __restrict__ partials)   // [NBLOCKS*2]
{
    const int wave = threadIdx.x >> 6;
    const int lane = threadIdx.x & 63;
    const int w    = blockIdx.x * 4 + wave;

    // Wave-uniform base -> scalar index loads (s_load), scalar compares.
    const int sbase = __builtin_amdgcn_readfirstlane(w * NPW);

    int i1[NPW], i2[NPW];
    #pragma unroll
    for (int j = 0; j < NPW; ++j) {
        i1[j] = b1[sbase + j];
        i2[j] = b2[sbase + j];
    }

    // Common g rows for this wave (always valid; usually the only ones needed).
    const float4 w11c = ((const float4*)(g1 + (size_t)i1[0] * 256))[lane];
    const float4 w12c = ((const float4*)(g2 + (size_t)i1[0] * 256))[lane];
    const float4 w22c = ((const float4*)(g2 + (size_t)i2[0] * 256))[lane];
    const float4 w21c = ((const float4*)(g1 + (size_t)i2[0] * 256))[lane];

    // All z rows up-front: 16 independent contiguous 1 KB loads in flight.
    float4 a1[NPW], a2[NPW];
    #pragma unroll
    for (int j = 0; j < NPW; ++j) {
        a1[j] = ((const float4*)(z1 + (size_t)(sbase + j) * 256))[lane];
        a2[j] = ((const float4*)(z2 + (size_t)(sbase + j) * 256))[lane];
    }

    float acc1 = 0.0f, acc2 = 0.0f;

    #pragma unroll
    for (int j = 0; j < NPW; ++j) {
        float4 v11 = w11c, v12 = w12c, v22 = w22c, v21 = w21c;
        if (i1[j] != i1[0]) {   // wave-uniform (scalar) branch, rare
            v11 = ((const float4*)(g1 + (size_t)i1[j] * 256))[lane];
            v12 = ((const float4*)(g2 + (size_t)i1[j] * 256))[lane];
        }
        if (i2[j] != i2[0]) {
            v22 = ((const float4*)(g2 + (size_t)i2[j] * 256))[lane];
            v21 = ((const float4*)(g1 + (size_t)i2[j] * 256))[lane];
        }

        float s11 = wave64_reduce(dot4(a1[j], v11));
        float c12 = wave64_reduce(dot4(a1[j], v12));
        float s22 = wave64_reduce(dot4(a2[j], v22));
        float c21 = wave64_reduce(dot4(a2[j], v21));

        if (lane == 63) {
            // f(s)-f(c) = softplus(-c) - softplus(-s)
            float d1 = spn(c12) - spn(s11);
            float d2 = spn(c21) - spn(s22);
            acc1 += d1 * d1;
            acc2 += d2 * d2;
        }
    }

    __shared__ float s1[4], s2[4];
    if (lane == 63) { s1[wave] = acc1; s2[wave] = acc2; }
    __syncthreads();

    if (threadIdx.x == 0) {
        partials[blockIdx.x * 2 + 0] = s1[0] + s1[1] + s1[2] + s1[3];
        partials[blockIdx.x * 2 + 1] = s2[0] + s2[1] + s2[2] + s2[3];
    }
}

__global__ __launch_bounds__(256) void jsd_reduce_kernel(
    const float* __restrict__ partials,
    float*       __restrict__ out)
{
    const int tid  = threadIdx.x;
    const int wave = tid >> 6;
    const int lane = tid & 63;

    float a = 0.0f, b = 0.0f;
    #pragma unroll
    for (int i = 0; i < NBLOCKS / 256; ++i) {
        a += partials[(i * 256 + tid) * 2 + 0];
        b += partials[(i * 256 + tid) * 2 + 1];
    }

    a = wave64_reduce(a);
    b = wave64_reduce(b);

    __shared__ float s1[4], s2[4];
    if (lane == 63) { s1[wave] = a; s2[wave] = b; }
    __syncthreads();

    if (tid == 0) {
        float t1 = s1[0] + s1[1] + s1[2] + s1[3];
        float t2 = s2[0] + s2[1] + s2[2] + s2[3];
        out[0] = sqrtf(t1) + sqrtf(t2);
    }
}

extern "C" void kernel_launch(void* const* d_in, const int* in_sizes, int n_in,
                              void* d_out, int out_size, void* d_ws, size_t ws_size,
                              hipStream_t stream) {
    const int*   b1 = (const int*)  d_in[0];
    const int*   b2 = (const int*)  d_in[1];
    const float* z1 = (const float*)d_in[2];
    const float* z2 = (const float*)d_in[3];
    const float* g1 = (const float*)d_in[4];
    const float* g2 = (const float*)d_in[5];
    float* out      = (float*)d_out;
    float* partials = (float*)d_ws;   // NBLOCKS*2 floats, fully overwritten

    jsd_dot_kernel<<<NBLOCKS, 256, 0, stream>>>(b1, b2, z1, z2, g1, g2, partials);
    jsd_reduce_kernel<<<1, 256, 0, stream>>>(partials, out);
}

// Round 6
// 157.408 us; speedup vs baseline: 1.0123x; 1.0123x over previous
//
#include <hip/hip_runtime.h>
#include <math.h>

// softplus(-p) = max(-p,0) + log(1+exp(-|p|)); fast intrinsics fine:
// threshold is 135 absolute on a ~6752 output (2%).
__device__ __forceinline__ float spn(float p) {
    return fmaxf(-p, 0.0f) + __logf(1.0f + __expf(-fabsf(p)));
}

__device__ __forceinline__ float dot4(float4 a, float4 b) {
    return a.x * b.x + a.y * b.y + a.z * b.z + a.w * b.w;
}

// Full 64-lane reduction, VALU-only (DPP). Result valid in lane 63.
__device__ __forceinline__ float wave64_reduce(float x) {
    int t;
    t = __builtin_amdgcn_update_dpp(0, __builtin_bit_cast(int, x), 0x111, 0xf, 0xf, true);
    x += __builtin_bit_cast(float, t);
    t = __builtin_amdgcn_update_dpp(0, __builtin_bit_cast(int, x), 0x112, 0xf, 0xf, true);
    x += __builtin_bit_cast(float, t);
    t = __builtin_amdgcn_update_dpp(0, __builtin_bit_cast(int, x), 0x114, 0xf, 0xf, true);
    x += __builtin_bit_cast(float, t);
    t = __builtin_amdgcn_update_dpp(0, __builtin_bit_cast(int, x), 0x118, 0xf, 0xf, true);
    x += __builtin_bit_cast(float, t);
    t = __builtin_amdgcn_update_dpp(0, __builtin_bit_cast(int, x), 0x142, 0xa, 0xf, true); // row_bcast15
    x += __builtin_bit_cast(float, t);
    t = __builtin_amdgcn_update_dpp(0, __builtin_bit_cast(int, x), 0x143, 0xc, 0xf, true); // row_bcast31
    x += __builtin_bit_cast(float, t);
    return x;   // lane 63 holds the full sum
}

typedef const void __attribute__((address_space(1)))* gas_ptr;
typedef void       __attribute__((address_space(3)))* las_ptr;

// Async global->LDS: 64 lanes x 16 B = one contiguous 1 KB row. The LDS
// destination is wave-uniform base + lane*16 (HW rule), which matches our
// unpadded row-contiguous layout. Consumes ZERO VGPRs -> the compiler
// cannot sink or serialize the prefetch burst.
__device__ __forceinline__ void stage_row(const float* grow, float* lrow, int lane) {
    __builtin_amdgcn_global_load_lds((gas_ptr)(grow + lane * 4), (las_ptr)lrow,
                                     16, 0, 0);
}

#define NBLOCKS 4096
#define NPB 16   // nodes per block
#define NPW 4    // nodes per wave: 4096 * 4 waves * 4 = 65536

__global__ __launch_bounds__(256) void jsd_dot_kernel(
    const int*   __restrict__ b1,
    const int*   __restrict__ b2,
    const float* __restrict__ z1,
    const float* __restrict__ z2,
    const float* __restrict__ g1,
    const float* __restrict__ g2,
    float*       __restrict__ partials)   // [NBLOCKS*2]
{
    __shared__ float zs1[NPB * 256];   // 16 KB
    __shared__ float zs2[NPB * 256];   // 16 KB

    const int wave = threadIdx.x >> 6;
    const int lane = threadIdx.x & 63;

    // Wave-uniform base -> scalar (s_load) index fetches.
    const int sbase = __builtin_amdgcn_readfirstlane(blockIdx.x * NPB + wave * NPW);

    // Burst: 8 async 1 KB z-row copies into LDS, all in flight at once.
    #pragma unroll
    for (int j = 0; j < NPW; ++j) {
        stage_row(z1 + (size_t)(sbase + j) * 256, &zs1[(wave * NPW + j) * 256], lane);
        stage_row(z2 + (size_t)(sbase + j) * 256, &zs2[(wave * NPW + j) * 256], lane);
    }

    int i1[NPW], i2[NPW];
    #pragma unroll
    for (int j = 0; j < NPW; ++j) {
        i1[j] = b1[sbase + j];
        i2[j] = b2[sbase + j];
    }

    __syncthreads();   // drains vmcnt -> staged rows valid

    float acc1 = 0.0f, acc2 = 0.0f;

    #pragma unroll
    for (int j = 0; j < NPW; ++j) {
        const float4 a1 = ((const float4*)&zs1[(wave * NPW + j) * 256])[lane];
        const float4 a2 = ((const float4*)&zs2[(wave * NPW + j) * 256])[lane];

        // g tables are 1 MB total -> L1/L2 resident; latency hidden by
        // 20 resident waves/CU of inter-block overlap.
        const float4 v11 = ((const float4*)(g1 + (size_t)i1[j] * 256))[lane];
        const float4 v12 = ((const float4*)(g2 + (size_t)i1[j] * 256))[lane];
        const float4 v22 = ((const float4*)(g2 + (size_t)i2[j] * 256))[lane];
        const float4 v21 = ((const float4*)(g1 + (size_t)i2[j] * 256))[lane];

        float s11 = wave64_reduce(dot4(a1, v11));
        float c12 = wave64_reduce(dot4(a1, v12));
        float s22 = wave64_reduce(dot4(a2, v22));
        float c21 = wave64_reduce(dot4(a2, v21));

        if (lane == 63) {
            // f(s)-f(c) = softplus(-c) - softplus(-s)
            float d1 = spn(c12) - spn(s11);
            float d2 = spn(c21) - spn(s22);
            acc1 += d1 * d1;
            acc2 += d2 * d2;
        }
    }

    __shared__ float s1[4], s2[4];
    if (lane == 63) { s1[wave] = acc1; s2[wave] = acc2; }
    __syncthreads();

    if (threadIdx.x == 0) {
        partials[blockIdx.x * 2 + 0] = s1[0] + s1[1] + s1[2] + s1[3];
        partials[blockIdx.x * 2 + 1] = s2[0] + s2[1] + s2[2] + s2[3];
    }
}

__global__ __launch_bounds__(256) void jsd_reduce_kernel(
    const float* __restrict__ partials,
    float*       __restrict__ out)
{
    const int tid  = threadIdx.x;
    const int wave = tid >> 6;
    const int lane = tid & 63;

    float a = 0.0f, b = 0.0f;
    #pragma unroll
    for (int i = 0; i < NBLOCKS / 256; ++i) {
        a += partials[(i * 256 + tid) * 2 + 0];
        b += partials[(i * 256 + tid) * 2 + 1];
    }

    a = wave64_reduce(a);
    b = wave64_reduce(b);

    __shared__ float s1[4], s2[4];
    if (lane == 63) { s1[wave] = a; s2[wave] = b; }
    __syncthreads();

    if (tid == 0) {
        float t1 = s1[0] + s1[1] + s1[2] + s1[3];
        float t2 = s2[0] + s2[1] + s2[2] + s2[3];
        out[0] = sqrtf(t1) + sqrtf(t2);
    }
}

extern "C" void kernel_launch(void* const* d_in, const int* in_sizes, int n_in,
                              void* d_out, int out_size, void* d_ws, size_t ws_size,
                              hipStream_t stream) {
    const int*   b1 = (const int*)  d_in[0];
    const int*   b2 = (const int*)  d_in[1];
    const float* z1 = (const float*)d_in[2];
    const float* z2 = (const float*)d_in[3];
    const float* g1 = (const float*)d_in[4];
    const float* g2 = (const float*)d_in[5];
    float* out      = (float*)d_out;
    float* partials = (float*)d_ws;   // NBLOCKS*2 floats, fully overwritten

    jsd_dot_kernel<<<NBLOCKS, 256, 0, stream>>>(b1, b2, z1, z2, g1, g2, partials);
    jsd_reduce_kernel<<<1, 256, 0, stream>>>(partials, out);
}